// Round 1
// baseline (880.006 us; speedup 1.0000x reference)
//
#include <hip/hip_runtime.h>
#include <hip/hip_bf16.h>

// int8-quantized 3x3 conv, N=8, C=K=32, H=W=512, pad=1, NCHW/OIHW.
// q = clip(rint(t*127/max|t|), -127, 127); out = conv(qx,qw)*sx*sw/127^2 + bias.
// Round 3: XCD-contiguous block swizzle (one image per XCD -> halo lines hit
// in-XCD L2), div-free staging loop, nontemporal output stores.

#define H 512
#define W 512
#define CIN 32
#define KOUT 32
#define NB 8
#define TH 16
#define TW 32
#define HW (H * W)

typedef int v4i  __attribute__((ext_vector_type(4)));
typedef int v16i __attribute__((ext_vector_type(16)));

__global__ void init_slots(unsigned* slots) {
    if (threadIdx.x < 2) slots[threadIdx.x] = 0u;
}

__device__ __forceinline__ float max4(float4 v) {
    return fmaxf(fmaxf(fabsf(v.x), fabsf(v.y)), fmaxf(fabsf(v.z), fabsf(v.w)));
}

// max|x| over 16.78M float4s. 2048 blocks x 256 thr, 4-deep unroll, indep accumulators.
__global__ __launch_bounds__(256)
void absmax_x(const float4* __restrict__ x, unsigned* slots, int n4) {
    const int stride = gridDim.x * blockDim.x;
    int i = blockIdx.x * blockDim.x + threadIdx.x;
    float m0 = 0.f, m1 = 0.f, m2 = 0.f, m3 = 0.f;
    for (; i + 3 * stride < n4; i += 4 * stride) {
        float4 a = x[i], b = x[i + stride], c = x[i + 2 * stride], d = x[i + 3 * stride];
        m0 = fmaxf(m0, max4(a)); m1 = fmaxf(m1, max4(b));
        m2 = fmaxf(m2, max4(c)); m3 = fmaxf(m3, max4(d));
    }
    for (; i < n4; i += stride) m0 = fmaxf(m0, max4(x[i]));
    float m = fmaxf(fmaxf(m0, m1), fmaxf(m2, m3));
    #pragma unroll
    for (int off = 32; off > 0; off >>= 1)
        m = fmaxf(m, __shfl_down(m, off));
    __shared__ float wm[4];
    int lane = threadIdx.x & 63, wid = threadIdx.x >> 6;
    if (lane == 0) wm[wid] = m;
    __syncthreads();
    if (threadIdx.x == 0) {
        m = fmaxf(fmaxf(wm[0], wm[1]), fmaxf(wm[2], wm[3]));
        atomicMax(slots, __float_as_uint(m));  // values >= 0: uint order == float order
    }
}

// One block: max|w| reduce -> slots[1], then quantize+pack w into qw[tap][kout][c] bytes.
__global__ __launch_bounds__(256)
void prep_w(const float* __restrict__ w, unsigned* slots, int* __restrict__ qw) {
    float m = 0.f;
    for (int i = threadIdx.x; i < KOUT * CIN * 9; i += 256)
        m = fmaxf(m, fabsf(w[i]));
    #pragma unroll
    for (int off = 32; off > 0; off >>= 1)
        m = fmaxf(m, __shfl_down(m, off));
    __shared__ float wm[4];
    __shared__ float swsh;
    int lane = threadIdx.x & 63, wid = threadIdx.x >> 6;
    if (lane == 0) wm[wid] = m;
    __syncthreads();
    if (threadIdx.x == 0) {
        float t = fmaxf(fmaxf(wm[0], wm[1]), fmaxf(wm[2], wm[3]));
        slots[1] = __float_as_uint(t);
        swsh = t;
    }
    __syncthreads();
    const float qs = 127.f / swsh;
    // dword d: tap = d>>8, k = (d>>3)&31, c4 = d&7; packs c = 4*c4 + 0..3
    for (int d = threadIdx.x; d < 9 * KOUT * 8; d += 256) {
        int tap = d >> 8, rem = d & 255, k = rem >> 3, c4 = rem & 7;
        int pk = 0;
        #pragma unroll
        for (int i = 0; i < 4; ++i) {
            int c = c4 * 4 + i;
            float q = fminf(fmaxf(rintf(w[(k * CIN + c) * 9 + tap] * qs), -127.f), 127.f);
            pk |= ((int)q & 255) << (8 * i);
        }
        qw[d] = pk;
    }
}

// Fused quantize-x + int8 MFMA conv + dequant + bias.
// Block: 256 thr (4 waves). Tile: 32 (x) x 16 (y), all 32 kout, one n.
// LDS act: [yy(18)][xx(34)][c(32)] bytes = 19584 B; B-frag = one ds_read_b128.
// Weights: fragments straight from global qw (L1-hot, 9216 B shared by all blocks).
// __launch_bounds__(256,8): pin VGPR<=64 so the LDS-limited 8 blocks/CU stay resident.
__global__ __launch_bounds__(256, 8)
void conv_mfma(const float* __restrict__ x, const int* __restrict__ qw,
               const float* __restrict__ bias, const unsigned* __restrict__ slots,
               float* __restrict__ out) {
    __shared__ int lds_a[18 * 34 * 8];  // dword per (pixel, c4)

    const int tid = threadIdx.x;

    // ---- XCD-contiguous swizzle: 4096 blocks, 8 XCDs -> 512 contiguous tiles
    // (= one full image n) per XCD, tx fastest. Halo lines shared between
    // x/y-neighbor tiles then hit the same XCD's L2 instead of re-fetching HBM.
    const int id   = (int)blockIdx.x + (int)gridDim.x * ((int)blockIdx.y + (int)gridDim.y * (int)blockIdx.z);
    const int work = (id & 7) * 512 + (id >> 3);   // 4096 % 8 == 0 -> bijective
    const int n    = work >> 9;                    // /512: image
    const int rem  = work & 511;
    const int y0   = (rem >> 4) * TH;              // ty = rem/16
    const int x0   = (rem & 15) * TW;              // tx fastest

    const float sx = __uint_as_float(slots[0]);
    const float sw = __uint_as_float(slots[1]);
    const float qsx = 127.f / sx;

    // ---- stage + quantize activation tile (18x34 halo, 32 c), div-free ----
    const float* xb = x + (size_t)n * CIN * HW;
    const int c4 = tid >> 5;               // 0..7: this thread's channel quad
    const int ln = tid & 31;               // 0..31: column lane within group
    const float* pb = xb + (size_t)(c4 * 4) * HW;
    const int gxm = x0 - 1 + ln;           // main column (xx = ln)
    const bool okxm = (unsigned)gxm < (unsigned)W;
    const int gxt = x0 + 31 + ln;          // tail column (xx = 32+ln, ln<2)
    const bool okxt = (ln < 2) & ((unsigned)gxt < (unsigned)W);
    const bool tail = ln < 2;

    for (int yy = 0; yy < 18; ++yy) {
        const int gy = y0 - 1 + yy;
        const bool oky = (unsigned)gy < (unsigned)H;
        const float* rowp = pb + (size_t)gy * W;
        {
            const bool ok = oky & okxm;
            int pk = 0;
            #pragma unroll
            for (int i = 0; i < 4; ++i) {
                float v = ok ? rowp[gxm + i * HW] : 0.f;
                int q = (int)fminf(fmaxf(rintf(v * qsx), -127.f), 127.f);
                pk |= (q & 255) << (8 * i);
            }
            lds_a[(yy * 34 + ln) * 8 + c4] = pk;
        }
        if (tail) {
            const bool ok = oky & okxt;
            int pk = 0;
            #pragma unroll
            for (int i = 0; i < 4; ++i) {
                float v = ok ? rowp[gxt + i * HW] : 0.f;
                int q = (int)fminf(fmaxf(rintf(v * qsx), -127.f), 127.f);
                pk |= (q & 255) << (8 * i);
            }
            lds_a[(yy * 34 + 32 + ln) * 8 + c4] = pk;
        }
    }

    // ---- weight A-fragments: A[m=kout][k=c], kout = lane&31, c = 16*half + j ----
    const int lane = tid & 63;
    const int kcol = lane & 31;     // kout for A; pixel-x col for B; out col
    const int half = lane >> 5;
    const v4i* qwv = (const v4i*)qw;  // 16B unit index: (tap*32 + kout)*2 + half
    v4i wf[9];
    #pragma unroll
    for (int t = 0; t < 9; ++t)
        wf[t] = qwv[(t * KOUT + kcol) * 2 + half];

    __syncthreads();

    // ---- MFMA main: wave handles 4 output rows; reuse LDS rows across dy ----
    const int wvid  = tid >> 6;
    const int ybase = wvid * 4;                 // local output rows ybase..ybase+3
    const v4i* lap = (const v4i*)lds_a;         // 16B unit: (yy*34 + xx)*2 + half

    v16i acc[4];
    #pragma unroll
    for (int r = 0; r < 4; ++r)
        #pragma unroll
        for (int q = 0; q < 16; ++q) acc[r][q] = 0;

    #pragma unroll
    for (int q = 0; q < 6; ++q) {               // LDS row = ybase + q (input rows)
        const int ly = ybase + q;
        v4i b[3];
        #pragma unroll
        for (int dx = 0; dx < 3; ++dx)
            b[dx] = lap[(ly * 34 + kcol + dx) * 2 + half];
        #pragma unroll
        for (int dy = 0; dy < 3; ++dy) {
            const int r = q - dy;               // output row using this LDS row
            if (r >= 0 && r < 4) {
                #pragma unroll
                for (int dx = 0; dx < 3; ++dx)
                    acc[r] = __builtin_amdgcn_mfma_i32_32x32x32_i8(
                        wf[dy * 3 + dx], b[dx], acc[r], 0, 0, 0);
            }
        }
    }

    // ---- epilogue: dequant + bias; D row m = kout, col n = x; nt stores
    // (output is write-once: don't let it evict halo lines from L2) ----
    const float dscale = sx * sw * (1.f / 16129.f);
    float bv[16];
    #pragma unroll
    for (int reg = 0; reg < 16; ++reg)
        bv[reg] = bias[(reg & 3) + 8 * (reg >> 2) + 4 * half];

    #pragma unroll
    for (int r = 0; r < 4; ++r) {
        const int ygl = y0 + ybase + r;
        float* ob = out + (((size_t)n * KOUT * H + ygl) * W) + x0 + kcol;
        #pragma unroll
        for (int reg = 0; reg < 16; ++reg) {
            const int m = (reg & 3) + 8 * (reg >> 2) + 4 * half;  // kout
            __builtin_nontemporal_store((float)acc[r][reg] * dscale + bv[reg],
                                        &ob[(size_t)m * HW]);
        }
    }
}

extern "C" void kernel_launch(void* const* d_in, const int* in_sizes, int n_in,
                              void* d_out, int out_size, void* d_ws, size_t ws_size,
                              hipStream_t stream) {
    const float* x    = (const float*)d_in[0];
    const float* w    = (const float*)d_in[1];
    const float* bias = (const float*)d_in[2];
    float* out        = (float*)d_out;
    unsigned* slots   = (unsigned*)d_ws;
    int* qw           = (int*)((char*)d_ws + 16);  // 9216 B packed int8 weights

    hipLaunchKernelGGL(init_slots, dim3(1), dim3(64), 0, stream, slots);
    hipLaunchKernelGGL(absmax_x, dim3(2048), dim3(256), 0, stream,
                       (const float4*)x, slots, (NB * CIN * H * W) / 4);
    hipLaunchKernelGGL(prep_w, dim3(1), dim3(256), 0, stream, w, slots, qw);
    dim3 grid(W / TW, H / TH, NB);
    hipLaunchKernelGGL(conv_mfma, grid, dim3(256), 0, stream, x, qw, bias, slots, out);
}

// Round 2
// 518.438 us; speedup vs baseline: 1.6974x; 1.6974x over previous
//
#include <hip/hip_runtime.h>
#include <hip/hip_bf16.h>

// int8-quantized 3x3 conv, N=8, C=K=32, H=W=512, pad=1, NCHW/OIHW.
// q = clip(rint(t*127/max|t|), -127, 127); out = conv(qx,qw)*sx*sw/127^2 + bias.
// Round 4: revert launch_bounds(256,8) -> (256). (256,8) capped the unified
// VGPR+AGPR budget at 64/wave, below the 64-reg accumulator alone -> acc
// spilled to scratch (WRITE_SIZE 262MB->1.08GB, conv 165->480us). Keep the
// XCD-contiguous swizzle, div-free staging, nontemporal stores.

#define H 512
#define W 512
#define CIN 32
#define KOUT 32
#define NB 8
#define TH 16
#define TW 32
#define HW (H * W)

typedef int v4i  __attribute__((ext_vector_type(4)));
typedef int v16i __attribute__((ext_vector_type(16)));

__global__ void init_slots(unsigned* slots) {
    if (threadIdx.x < 2) slots[threadIdx.x] = 0u;
}

__device__ __forceinline__ float max4(float4 v) {
    return fmaxf(fmaxf(fabsf(v.x), fabsf(v.y)), fmaxf(fabsf(v.z), fabsf(v.w)));
}

// max|x| over 16.78M float4s. 2048 blocks x 256 thr, 4-deep unroll, indep accumulators.
__global__ __launch_bounds__(256)
void absmax_x(const float4* __restrict__ x, unsigned* slots, int n4) {
    const int stride = gridDim.x * blockDim.x;
    int i = blockIdx.x * blockDim.x + threadIdx.x;
    float m0 = 0.f, m1 = 0.f, m2 = 0.f, m3 = 0.f;
    for (; i + 3 * stride < n4; i += 4 * stride) {
        float4 a = x[i], b = x[i + stride], c = x[i + 2 * stride], d = x[i + 3 * stride];
        m0 = fmaxf(m0, max4(a)); m1 = fmaxf(m1, max4(b));
        m2 = fmaxf(m2, max4(c)); m3 = fmaxf(m3, max4(d));
    }
    for (; i < n4; i += stride) m0 = fmaxf(m0, max4(x[i]));
    float m = fmaxf(fmaxf(m0, m1), fmaxf(m2, m3));
    #pragma unroll
    for (int off = 32; off > 0; off >>= 1)
        m = fmaxf(m, __shfl_down(m, off));
    __shared__ float wm[4];
    int lane = threadIdx.x & 63, wid = threadIdx.x >> 6;
    if (lane == 0) wm[wid] = m;
    __syncthreads();
    if (threadIdx.x == 0) {
        m = fmaxf(fmaxf(wm[0], wm[1]), fmaxf(wm[2], wm[3]));
        atomicMax(slots, __float_as_uint(m));  // values >= 0: uint order == float order
    }
}

// One block: max|w| reduce -> slots[1], then quantize+pack w into qw[tap][kout][c] bytes.
__global__ __launch_bounds__(256)
void prep_w(const float* __restrict__ w, unsigned* slots, int* __restrict__ qw) {
    float m = 0.f;
    for (int i = threadIdx.x; i < KOUT * CIN * 9; i += 256)
        m = fmaxf(m, fabsf(w[i]));
    #pragma unroll
    for (int off = 32; off > 0; off >>= 1)
        m = fmaxf(m, __shfl_down(m, off));
    __shared__ float wm[4];
    __shared__ float swsh;
    int lane = threadIdx.x & 63, wid = threadIdx.x >> 6;
    if (lane == 0) wm[wid] = m;
    __syncthreads();
    if (threadIdx.x == 0) {
        float t = fmaxf(fmaxf(wm[0], wm[1]), fmaxf(wm[2], wm[3]));
        slots[1] = __float_as_uint(t);
        swsh = t;
    }
    __syncthreads();
    const float qs = 127.f / swsh;
    // dword d: tap = d>>8, k = (d>>3)&31, c4 = d&7; packs c = 4*c4 + 0..3
    for (int d = threadIdx.x; d < 9 * KOUT * 8; d += 256) {
        int tap = d >> 8, rem = d & 255, k = rem >> 3, c4 = rem & 7;
        int pk = 0;
        #pragma unroll
        for (int i = 0; i < 4; ++i) {
            int c = c4 * 4 + i;
            float q = fminf(fmaxf(rintf(w[(k * CIN + c) * 9 + tap] * qs), -127.f), 127.f);
            pk |= ((int)q & 255) << (8 * i);
        }
        qw[d] = pk;
    }
}

// Fused quantize-x + int8 MFMA conv + dequant + bias.
// Block: 256 thr (4 waves). Tile: 32 (x) x 16 (y), all 32 kout, one n.
// LDS act: [yy(18)][xx(34)][c(32)] bytes = 19584 B; B-frag = one ds_read_b128.
// Weights: fragments straight from global qw (L1-hot, 9216 B shared by all blocks).
// NOTE: no min-waves launch bound — acc[4] alone is 64 regs in the unified
// VGPR/AGPR file; (256,8) forced VGPR=32 and spilled acc to scratch (3x slowdown).
__global__ __launch_bounds__(256)
void conv_mfma(const float* __restrict__ x, const int* __restrict__ qw,
               const float* __restrict__ bias, const unsigned* __restrict__ slots,
               float* __restrict__ out) {
    __shared__ int lds_a[18 * 34 * 8];  // dword per (pixel, c4)

    const int tid = threadIdx.x;

    // ---- XCD-contiguous swizzle: 4096 blocks, 8 XCDs -> 512 contiguous tiles
    // (= one full image n) per XCD, tx fastest. Halo lines shared between
    // x/y-neighbor tiles then hit the same XCD's L2 instead of re-fetching HBM.
    const int id   = (int)blockIdx.x + (int)gridDim.x * ((int)blockIdx.y + (int)gridDim.y * (int)blockIdx.z);
    const int work = (id & 7) * 512 + (id >> 3);   // 4096 % 8 == 0 -> bijective
    const int n    = work >> 9;                    // /512: image
    const int rem  = work & 511;
    const int y0   = (rem >> 4) * TH;              // ty = rem/16
    const int x0   = (rem & 15) * TW;              // tx fastest

    const float sx = __uint_as_float(slots[0]);
    const float sw = __uint_as_float(slots[1]);
    const float qsx = 127.f / sx;

    // ---- stage + quantize activation tile (18x34 halo, 32 c), div-free ----
    const float* xb = x + (size_t)n * CIN * HW;
    const int c4 = tid >> 5;               // 0..7: this thread's channel quad
    const int ln = tid & 31;               // 0..31: column lane within group
    const float* pb = xb + (size_t)(c4 * 4) * HW;
    const int gxm = x0 - 1 + ln;           // main column (xx = ln)
    const bool okxm = (unsigned)gxm < (unsigned)W;
    const int gxt = x0 + 31 + ln;          // tail column (xx = 32+ln, ln<2)
    const bool okxt = (ln < 2) & ((unsigned)gxt < (unsigned)W);
    const bool tail = ln < 2;

    for (int yy = 0; yy < 18; ++yy) {
        const int gy = y0 - 1 + yy;
        const bool oky = (unsigned)gy < (unsigned)H;
        const float* rowp = pb + (size_t)gy * W;
        {
            const bool ok = oky & okxm;
            int pk = 0;
            #pragma unroll
            for (int i = 0; i < 4; ++i) {
                float v = ok ? rowp[gxm + i * HW] : 0.f;
                int q = (int)fminf(fmaxf(rintf(v * qsx), -127.f), 127.f);
                pk |= (q & 255) << (8 * i);
            }
            lds_a[(yy * 34 + ln) * 8 + c4] = pk;
        }
        if (tail) {
            const bool ok = oky & okxt;
            int pk = 0;
            #pragma unroll
            for (int i = 0; i < 4; ++i) {
                float v = ok ? rowp[gxt + i * HW] : 0.f;
                int q = (int)fminf(fmaxf(rintf(v * qsx), -127.f), 127.f);
                pk |= (q & 255) << (8 * i);
            }
            lds_a[(yy * 34 + 32 + ln) * 8 + c4] = pk;
        }
    }

    // ---- weight A-fragments: A[m=kout][k=c], kout = lane&31, c = 16*half + j ----
    const int lane = tid & 63;
    const int kcol = lane & 31;     // kout for A; pixel-x col for B; out col
    const int half = lane >> 5;
    const v4i* qwv = (const v4i*)qw;  // 16B unit index: (tap*32 + kout)*2 + half
    v4i wf[9];
    #pragma unroll
    for (int t = 0; t < 9; ++t)
        wf[t] = qwv[(t * KOUT + kcol) * 2 + half];

    __syncthreads();

    // ---- MFMA main: wave handles 4 output rows; reuse LDS rows across dy ----
    const int wvid  = tid >> 6;
    const int ybase = wvid * 4;                 // local output rows ybase..ybase+3
    const v4i* lap = (const v4i*)lds_a;         // 16B unit: (yy*34 + xx)*2 + half

    v16i acc[4];
    #pragma unroll
    for (int r = 0; r < 4; ++r)
        #pragma unroll
        for (int q = 0; q < 16; ++q) acc[r][q] = 0;

    #pragma unroll
    for (int q = 0; q < 6; ++q) {               // LDS row = ybase + q (input rows)
        const int ly = ybase + q;
        v4i b[3];
        #pragma unroll
        for (int dx = 0; dx < 3; ++dx)
            b[dx] = lap[(ly * 34 + kcol + dx) * 2 + half];
        #pragma unroll
        for (int dy = 0; dy < 3; ++dy) {
            const int r = q - dy;               // output row using this LDS row
            if (r >= 0 && r < 4) {
                #pragma unroll
                for (int dx = 0; dx < 3; ++dx)
                    acc[r] = __builtin_amdgcn_mfma_i32_32x32x32_i8(
                        wf[dy * 3 + dx], b[dx], acc[r], 0, 0, 0);
            }
        }
    }

    // ---- epilogue: dequant + bias; D row m = kout, col n = x; nt stores
    // (output is write-once: don't let it evict halo lines from L2) ----
    const float dscale = sx * sw * (1.f / 16129.f);
    float bv[16];
    #pragma unroll
    for (int reg = 0; reg < 16; ++reg)
        bv[reg] = bias[(reg & 3) + 8 * (reg >> 2) + 4 * half];

    #pragma unroll
    for (int r = 0; r < 4; ++r) {
        const int ygl = y0 + ybase + r;
        float* ob = out + (((size_t)n * KOUT * H + ygl) * W) + x0 + kcol;
        #pragma unroll
        for (int reg = 0; reg < 16; ++reg) {
            const int m = (reg & 3) + 8 * (reg >> 2) + 4 * half;  // kout
            __builtin_nontemporal_store((float)acc[r][reg] * dscale + bv[reg],
                                        &ob[(size_t)m * HW]);
        }
    }
}

extern "C" void kernel_launch(void* const* d_in, const int* in_sizes, int n_in,
                              void* d_out, int out_size, void* d_ws, size_t ws_size,
                              hipStream_t stream) {
    const float* x    = (const float*)d_in[0];
    const float* w    = (const float*)d_in[1];
    const float* bias = (const float*)d_in[2];
    float* out        = (float*)d_out;
    unsigned* slots   = (unsigned*)d_ws;
    int* qw           = (int*)((char*)d_ws + 16);  // 9216 B packed int8 weights

    hipLaunchKernelGGL(init_slots, dim3(1), dim3(64), 0, stream, slots);
    hipLaunchKernelGGL(absmax_x, dim3(2048), dim3(256), 0, stream,
                       (const float4*)x, slots, (NB * CIN * H * W) / 4);
    hipLaunchKernelGGL(prep_w, dim3(1), dim3(256), 0, stream, w, slots, qw);
    dim3 grid(W / TW, H / TH, NB);
    hipLaunchKernelGGL(conv_mfma, grid, dim3(256), 0, stream, x, qw, bias, slots, out);
}

// Round 4
// 517.122 us; speedup vs baseline: 1.7017x; 1.0025x over previous
//
#include <hip/hip_runtime.h>
#include <hip/hip_bf16.h>

// int8-quantized 3x3 conv, N=8, C=K=32, H=W=512, pad=1, NCHW/OIHW.
// q = clip(rint(t*127/max|t|), -127, 127); out = conv(qx,qw)*sx*sw/127^2 + bias.
// Round 6: identical to round 5 (bench infra failed; no data). LDS half-bit
// XOR swizzle on the activation tile (staging-write bank conflicts 8-deep ->
// 4-deep; b128 reads stay at the bank floor); init_slots folded into prep_w.

#define H 512
#define W 512
#define CIN 32
#define KOUT 32
#define NB 8
#define TH 16
#define TW 32
#define HW (H * W)

typedef int v4i  __attribute__((ext_vector_type(4)));
typedef int v16i __attribute__((ext_vector_type(16)));

__device__ __forceinline__ float max4(float4 v) {
    return fmaxf(fmaxf(fabsf(v.x), fabsf(v.y)), fmaxf(fabsf(v.z), fabsf(v.w)));
}

// max|x| over 16.78M float4s. 2048 blocks x 256 thr, 4-deep unroll, indep accumulators.
__global__ __launch_bounds__(256)
void absmax_x(const float4* __restrict__ x, unsigned* slots, int n4) {
    const int stride = gridDim.x * blockDim.x;
    int i = blockIdx.x * blockDim.x + threadIdx.x;
    float m0 = 0.f, m1 = 0.f, m2 = 0.f, m3 = 0.f;
    for (; i + 3 * stride < n4; i += 4 * stride) {
        float4 a = x[i], b = x[i + stride], c = x[i + 2 * stride], d = x[i + 3 * stride];
        m0 = fmaxf(m0, max4(a)); m1 = fmaxf(m1, max4(b));
        m2 = fmaxf(m2, max4(c)); m3 = fmaxf(m3, max4(d));
    }
    for (; i < n4; i += stride) m0 = fmaxf(m0, max4(x[i]));
    float m = fmaxf(fmaxf(m0, m1), fmaxf(m2, m3));
    #pragma unroll
    for (int off = 32; off > 0; off >>= 1)
        m = fmaxf(m, __shfl_down(m, off));
    __shared__ float wm[4];
    int lane = threadIdx.x & 63, wid = threadIdx.x >> 6;
    if (lane == 0) wm[wid] = m;
    __syncthreads();
    if (threadIdx.x == 0) {
        m = fmaxf(fmaxf(wm[0], wm[1]), fmaxf(wm[2], wm[3]));
        atomicMax(slots, __float_as_uint(m));  // values >= 0: uint order == float order
    }
}

// One block. Zeroes slots[0] (runs FIRST in stream order, before absmax),
// then max|w| reduce -> slots[1], then quantize+pack w into qw[tap][kout][c].
__global__ __launch_bounds__(256)
void prep_w(const float* __restrict__ w, unsigned* slots, int* __restrict__ qw) {
    if (threadIdx.x == 0) slots[0] = 0u;   // init for absmax's atomicMax
    float m = 0.f;
    for (int i = threadIdx.x; i < KOUT * CIN * 9; i += 256)
        m = fmaxf(m, fabsf(w[i]));
    #pragma unroll
    for (int off = 32; off > 0; off >>= 1)
        m = fmaxf(m, __shfl_down(m, off));
    __shared__ float wm[4];
    __shared__ float swsh;
    int lane = threadIdx.x & 63, wid = threadIdx.x >> 6;
    if (lane == 0) wm[wid] = m;
    __syncthreads();
    if (threadIdx.x == 0) {
        float t = fmaxf(fmaxf(wm[0], wm[1]), fmaxf(wm[2], wm[3]));
        slots[1] = __float_as_uint(t);
        swsh = t;
    }
    __syncthreads();
    const float qs = 127.f / swsh;
    // dword d: tap = d>>8, k = (d>>3)&31, c4 = d&7; packs c = 4*c4 + 0..3
    for (int d = threadIdx.x; d < 9 * KOUT * 8; d += 256) {
        int tap = d >> 8, rem = d & 255, k = rem >> 3, c4 = rem & 7;
        int pk = 0;
        #pragma unroll
        for (int i = 0; i < 4; ++i) {
            int c = c4 * 4 + i;
            float q = fminf(fmaxf(rintf(w[(k * CIN + c) * 9 + tap] * qs), -127.f), 127.f);
            pk |= ((int)q & 255) << (8 * i);
        }
        qw[d] = pk;
    }
}

// Fused quantize-x + int8 MFMA conv + dequant + bias.
// Block: 256 thr (4 waves). Tile: 32 (x) x 16 (y), all 32 kout, one n.
// LDS act: [yy(18)][xx(34)][c(32)] bytes, 16B-unit swizzle: unit(pix,h) =
//   pix*2 + (h ^ ((pix>>2)&1)). Writes then touch 16 banks (4-deep) instead of
//   8 banks (8-deep); b128 reads remain at the bank floor.
// Weights: fragments straight from global qw (L1-hot, 9216 B shared by all blocks).
// NOTE: no min-waves launch bound — acc[4] alone is 64 regs in the unified
// VGPR/AGPR file; (256,8) forced VGPR=32 and spilled acc to scratch (3x slowdown).
__global__ __launch_bounds__(256)
void conv_mfma(const float* __restrict__ x, const int* __restrict__ qw,
               const float* __restrict__ bias, const unsigned* __restrict__ slots,
               float* __restrict__ out) {
    __shared__ int lds_a[18 * 34 * 8];  // dword per (pixel, c4), swizzled

    const int tid = threadIdx.x;

    // ---- XCD-contiguous swizzle: 4096 blocks, 8 XCDs -> 512 contiguous tiles
    // (= one full image n) per XCD, tx fastest. Halo lines shared between
    // x/y-neighbor tiles then hit the same XCD's L2 instead of re-fetching HBM.
    const int id   = (int)blockIdx.x + (int)gridDim.x * ((int)blockIdx.y + (int)gridDim.y * (int)blockIdx.z);
    const int work = (id & 7) * 512 + (id >> 3);   // 4096 % 8 == 0 -> bijective
    const int n    = work >> 9;                    // /512: image
    const int rem  = work & 511;
    const int y0   = (rem >> 4) * TH;              // ty = rem/16
    const int x0   = (rem & 15) * TW;              // tx fastest

    const float sx = __uint_as_float(slots[0]);
    const float sw = __uint_as_float(slots[1]);
    const float qsx = 127.f / sx;

    // ---- stage + quantize activation tile (18x34 halo, 32 c), div-free ----
    const float* xb = x + (size_t)n * CIN * HW;
    const int c4 = tid >> 5;               // 0..7: this thread's channel quad
    const int ln = tid & 31;               // 0..31: column lane within group
    const float* pb = xb + (size_t)(c4 * 4) * HW;
    const int gxm = x0 - 1 + ln;           // main column (xx = ln)
    const bool okxm = (unsigned)gxm < (unsigned)W;
    const int gxt = x0 + 31 + ln;          // tail column (xx = 32+ln, ln<2)
    const bool okxt = (ln < 2) & ((unsigned)gxt < (unsigned)W);
    const bool tail = ln < 2;

    for (int yy = 0; yy < 18; ++yy) {
        const int gy = y0 - 1 + yy;
        const bool oky = (unsigned)gy < (unsigned)H;
        const float* rowp = pb + (size_t)gy * W;
        {
            const bool ok = oky & okxm;
            const int pix = yy * 34 + ln;
            int pk = 0;
            #pragma unroll
            for (int i = 0; i < 4; ++i) {
                float v = ok ? rowp[gxm + i * HW] : 0.f;
                int q = (int)fminf(fmaxf(rintf(v * qsx), -127.f), 127.f);
                pk |= (q & 255) << (8 * i);
            }
            lds_a[pix * 8 + (c4 ^ (((pix >> 2) & 1) << 2))] = pk;
        }
        if (tail) {
            const bool ok = oky & okxt;
            const int pix = yy * 34 + 32 + ln;
            int pk = 0;
            #pragma unroll
            for (int i = 0; i < 4; ++i) {
                float v = ok ? rowp[gxt + i * HW] : 0.f;
                int q = (int)fminf(fmaxf(rintf(v * qsx), -127.f), 127.f);
                pk |= (q & 255) << (8 * i);
            }
            lds_a[pix * 8 + (c4 ^ (((pix >> 2) & 1) << 2))] = pk;
        }
    }

    // ---- weight A-fragments: A[m=kout][k=c], kout = lane&31, c = 16*half + j ----
    const int lane = tid & 63;
    const int kcol = lane & 31;     // kout for A; pixel-x col for B; out col
    const int half = lane >> 5;
    const v4i* qwv = (const v4i*)qw;  // 16B unit index: (tap*32 + kout)*2 + half
    v4i wf[9];
    #pragma unroll
    for (int t = 0; t < 9; ++t)
        wf[t] = qwv[(t * KOUT + kcol) * 2 + half];

    __syncthreads();

    // ---- MFMA main: wave handles 4 output rows; reuse LDS rows across dy ----
    const int wvid  = tid >> 6;
    const int ybase = wvid * 4;                 // local output rows ybase..ybase+3
    const v4i* lap = (const v4i*)lds_a;         // 16B unit: pix*2 + (half ^ ((pix>>2)&1))

    v16i acc[4];
    #pragma unroll
    for (int r = 0; r < 4; ++r)
        #pragma unroll
        for (int q = 0; q < 16; ++q) acc[r][q] = 0;

    #pragma unroll
    for (int q = 0; q < 6; ++q) {               // LDS row = ybase + q (input rows)
        const int ly = ybase + q;
        v4i b[3];
        #pragma unroll
        for (int dx = 0; dx < 3; ++dx) {
            const int pix = ly * 34 + kcol + dx;
            b[dx] = lap[pix * 2 + (half ^ ((pix >> 2) & 1))];
        }
        #pragma unroll
        for (int dy = 0; dy < 3; ++dy) {
            const int r = q - dy;               // output row using this LDS row
            if (r >= 0 && r < 4) {
                #pragma unroll
                for (int dx = 0; dx < 3; ++dx)
                    acc[r] = __builtin_amdgcn_mfma_i32_32x32x32_i8(
                        wf[dy * 3 + dx], b[dx], acc[r], 0, 0, 0);
            }
        }
    }

    // ---- epilogue: dequant + bias; D row m = kout, col n = x; nt stores
    // (output is write-once: don't let it evict halo lines from L2) ----
    const float dscale = sx * sw * (1.f / 16129.f);
    float bv[16];
    #pragma unroll
    for (int reg = 0; reg < 16; ++reg)
        bv[reg] = bias[(reg & 3) + 8 * (reg >> 2) + 4 * half];

    #pragma unroll
    for (int r = 0; r < 4; ++r) {
        const int ygl = y0 + ybase + r;
        float* ob = out + (((size_t)n * KOUT * H + ygl) * W) + x0 + kcol;
        #pragma unroll
        for (int reg = 0; reg < 16; ++reg) {
            const int m = (reg & 3) + 8 * (reg >> 2) + 4 * half;  // kout
            __builtin_nontemporal_store((float)acc[r][reg] * dscale + bv[reg],
                                        &ob[(size_t)m * HW]);
        }
    }
}

extern "C" void kernel_launch(void* const* d_in, const int* in_sizes, int n_in,
                              void* d_out, int out_size, void* d_ws, size_t ws_size,
                              hipStream_t stream) {
    const float* x    = (const float*)d_in[0];
    const float* w    = (const float*)d_in[1];
    const float* bias = (const float*)d_in[2];
    float* out        = (float*)d_out;
    unsigned* slots   = (unsigned*)d_ws;
    int* qw           = (int*)((char*)d_ws + 16);  // 9216 B packed int8 weights

    // prep_w first: zeroes slots[0] before absmax's atomicMax (stream-ordered),
    // computes slots[1] and packs weights. Saves the init_slots launch.
    hipLaunchKernelGGL(prep_w, dim3(1), dim3(256), 0, stream, w, slots, qw);
    hipLaunchKernelGGL(absmax_x, dim3(2048), dim3(256), 0, stream,
                       (const float4*)x, slots, (NB * CIN * H * W) / 4);
    dim3 grid(W / TW, H / TH, NB);
    hipLaunchKernelGGL(conv_mfma, grid, dim3(256), 0, stream, x, qw, bias, slots, out);
}